// Round 1
// baseline (14276.636 us; speedup 1.0000x reference)
//
#include <hip/hip_runtime.h>

#define HSTEPS 8640
#define HID 128
#define BATCH 16
#define NTHR 512

typedef _Float16 h16;
typedef __attribute__((ext_vector_type(2))) _Float16 h16x2;
typedef __attribute__((ext_vector_type(8))) _Float16 h16x8;

#if __has_builtin(__builtin_amdgcn_fdot2)
#define FDOT2(a, b, c) __builtin_amdgcn_fdot2((a), (b), (c), false)
#else
static __device__ __forceinline__ float FDOT2(h16x2 a, h16x2 b, float c) {
    return c + (float)a[0] * (float)b[0] + (float)a[1] * (float)b[1];
}
#endif

static __device__ __forceinline__ float sigm(float x) {
    return __builtin_amdgcn_rcpf(1.0f + __expf(-x));
}
static __device__ __forceinline__ float tanh_f(float x) {
    float ax = __builtin_fabsf(x);
    float e = __expf(2.0f * ax);
    float r = 1.0f - 2.0f * __builtin_amdgcn_rcpf(e + 1.0f);
    return __builtin_copysignf(r, x);
}

// One block per batch element. 512 threads; thread g owns gate-row g of both
// layers. Weights live in registers as f16 pairs (3 x 64 VGPRs), h vectors are
// broadcast from LDS as f16, accumulation in fp32 via v_dot2_f32_f16.
// c-state: thread j (<128) holds c0[j]; thread 128+j holds c1[j].
__global__ __launch_bounds__(NTHR, 2) void lstm2_kernel(
    const float* __restrict__ y0, const float* __restrict__ h0in,
    const float* __restrict__ c0in, const float* __restrict__ Wih0,
    const float* __restrict__ Whh0, const float* __restrict__ bih0,
    const float* __restrict__ bhh0, const float* __restrict__ Wih1,
    const float* __restrict__ Whh1, const float* __restrict__ bih1,
    const float* __restrict__ bhh1, const float* __restrict__ fcw,
    const float* __restrict__ fcb, float* __restrict__ out) {
    const int b = blockIdx.x;
    const int t = threadIdx.x;

    __shared__ __align__(16) h16 h0h[HID];   // layer0 h (f16) for broadcast
    __shared__ __align__(16) h16 h1h[HID];   // layer1 h (f16)
    __shared__ float gbuf[4 * HID];          // gate staging
    __shared__ float ypart[2];               // fc partial sums (2 waves)

    // ---- load this thread's weight rows into registers as f16 pairs ----
    h16x2 w0[64], w1[64], w2[64];
#pragma unroll
    for (int i = 0; i < 64; ++i) {
        float2 a = *(const float2*)(Whh0 + t * HID + 2 * i);
        w0[i] = h16x2{(h16)a.x, (h16)a.y};
        float2 bq = *(const float2*)(Wih1 + t * HID + 2 * i);
        w1[i] = h16x2{(h16)bq.x, (h16)bq.y};
        float2 cq = *(const float2*)(Whh1 + t * HID + 2 * i);
        w2[i] = h16x2{(h16)cq.x, (h16)cq.y};
    }
    const float bias0 = bih0[t] + bhh0[t];
    const float bias1 = bih1[t] + bhh1[t];
    const float wih0t = Wih0[t];  // W_ih0 is (512,1)
    const float fcb_ = fcb[0];

    float cst = 0.0f;   // this thread's cell-state element (if t<256)
    float fcwj = 0.0f;  // fc weight for layer-1 act threads
    if (t < HID) {
        cst = c0in[b * HID + t];  // layer 0
        h0h[t] = (h16)h0in[b * HID + t];
    } else if (t < 2 * HID) {
        int j = t - HID;
        cst = c0in[(BATCH + b) * HID + j];  // layer 1
        h1h[j] = (h16)h0in[(BATCH + b) * HID + j];
        fcwj = fcw[j];
    }
    if (t == 0) {
        ypart[0] = y0[b] - fcb_;  // so y = p0+p1+fcb gives y0 on step 0
        ypart[1] = 0.0f;
    }
    __syncthreads();

    float* outb = out + (size_t)b * HSTEPS;

#pragma unroll 1
    for (int step = 0; step < HSTEPS; ++step) {
        // ---- y from previous step's fc partials; layer-0 matvec ----
        float y = ypart[0] + ypart[1] + fcb_;
        if (t == 0 && step > 0) outb[step - 1] = y;

        float a0 = __builtin_fmaf(wih0t, y, bias0);
        float a1 = 0.0f, a2 = 0.0f, a3 = 0.0f;
#pragma unroll
        for (int i = 0; i < 16; ++i) {
            h16x8 hv = *(const h16x8*)(&h0h[i * 8]);
            h16x2 p0 = {hv[0], hv[1]}, p1 = {hv[2], hv[3]};
            h16x2 p2 = {hv[4], hv[5]}, p3 = {hv[6], hv[7]};
            a0 = FDOT2(w0[4 * i + 0], p0, a0);
            a1 = FDOT2(w0[4 * i + 1], p1, a1);
            a2 = FDOT2(w0[4 * i + 2], p2, a2);
            a3 = FDOT2(w0[4 * i + 3], p3, a3);
        }
        gbuf[t] = (a0 + a1) + (a2 + a3);
        __syncthreads();  // B1: gates0 ready

        // ---- layer-0 activations (threads 0..127, waves 0-1) ----
        if (t < HID) {
            float gi = gbuf[t], gf = gbuf[t + 128];
            float gg = gbuf[t + 256], go = gbuf[t + 384];
            float si = sigm(gi), sf = sigm(gf), so = sigm(go);
            float tg = tanh_f(gg);
            cst = __builtin_fmaf(sf, cst, si * tg);
            float h = so * tanh_f(cst);
            h0h[t] = (h16)h;
        }
        __syncthreads();  // B2: h0h ready

        // ---- layer-1 matvecs: Wih1 @ h0n + Whh1 @ h1 ----
        float b0 = bias1, b1 = 0.0f, b2 = 0.0f, b3 = 0.0f;
#pragma unroll
        for (int i = 0; i < 16; ++i) {
            h16x8 hv = *(const h16x8*)(&h0h[i * 8]);
            h16x2 p0 = {hv[0], hv[1]}, p1 = {hv[2], hv[3]};
            h16x2 p2 = {hv[4], hv[5]}, p3 = {hv[6], hv[7]};
            b0 = FDOT2(w1[4 * i + 0], p0, b0);
            b1 = FDOT2(w1[4 * i + 1], p1, b1);
            b2 = FDOT2(w1[4 * i + 2], p2, b2);
            b3 = FDOT2(w1[4 * i + 3], p3, b3);
        }
#pragma unroll
        for (int i = 0; i < 16; ++i) {
            h16x8 hv = *(const h16x8*)(&h1h[i * 8]);
            h16x2 p0 = {hv[0], hv[1]}, p1 = {hv[2], hv[3]};
            h16x2 p2 = {hv[4], hv[5]}, p3 = {hv[6], hv[7]};
            b0 = FDOT2(w2[4 * i + 0], p0, b0);
            b1 = FDOT2(w2[4 * i + 1], p1, b1);
            b2 = FDOT2(w2[4 * i + 2], p2, b2);
            b3 = FDOT2(w2[4 * i + 3], p3, b3);
        }
        gbuf[t] = (b0 + b1) + (b2 + b3);
        __syncthreads();  // B3: gates1 ready

        // ---- layer-1 activations + fused fc reduction (threads 128..255) ----
        if (t >= HID && t < 2 * HID) {
            int j = t - HID;
            float gi = gbuf[j], gf = gbuf[j + 128];
            float gg = gbuf[j + 256], go = gbuf[j + 384];
            float si = sigm(gi), sf = sigm(gf), so = sigm(go);
            float tg = tanh_f(gg);
            cst = __builtin_fmaf(sf, cst, si * tg);
            float h = so * tanh_f(cst);
            h1h[j] = (h16)h;
            float part = fcwj * h;
#pragma unroll
            for (int off = 32; off >= 1; off >>= 1)
                part += __shfl_down(part, off, 64);
            if ((t & 63) == 0) ypart[(t - HID) >> 6] = part;
        }
        __syncthreads();  // B4: h1h + ypart ready
    }

    if (t == 0) {
        float y = ypart[0] + ypart[1] + fcb_;
        outb[HSTEPS - 1] = y;
    }
}

extern "C" void kernel_launch(void* const* d_in, const int* in_sizes, int n_in,
                              void* d_out, int out_size, void* d_ws,
                              size_t ws_size, hipStream_t stream) {
    const float* y0 = (const float*)d_in[0];
    const float* h0 = (const float*)d_in[1];
    const float* c0 = (const float*)d_in[2];
    const float* Wih0 = (const float*)d_in[3];
    const float* Whh0 = (const float*)d_in[4];
    const float* bih0 = (const float*)d_in[5];
    const float* bhh0 = (const float*)d_in[6];
    const float* Wih1 = (const float*)d_in[7];
    const float* Whh1 = (const float*)d_in[8];
    const float* bih1 = (const float*)d_in[9];
    const float* bhh1 = (const float*)d_in[10];
    const float* fcw = (const float*)d_in[11];
    const float* fcb = (const float*)d_in[12];
    float* out = (float*)d_out;

    lstm2_kernel<<<dim3(BATCH), dim3(NTHR), 0, stream>>>(
        y0, h0, c0, Wih0, Whh0, bih0, bhh0, Wih1, Whh1, bih1, bhh1, fcw, fcb,
        out);
}